// Round 3
// baseline (1941.692 us; speedup 1.0000x reference)
//
#include <hip/hip_runtime.h>
#include <hip/hip_bf16.h>

// ---------------------------------------------------------------------------
// CombineMultiOutputModelWeightedConcat: 9-stage MLP w/ training-mode BN.
// Dtype-agnostic: a detect kernel votes on x1f's bit patterns (fp32 vs bf16),
// params are up-converted to an fp32 staging area, stage-A loads and head
// stores dual-path on the flag. Intermediates are bf16 (fp32 compute).
// Fusion: GEMM epilogue does bias+relu+store+column sum/sumsq atomics;
// consumer load path applies producer BN; combine stage folds the softmax
// gate weights into its load (xw never materialized).
// Workspace (lifetime-aliased): [0,64M) z1/z2 -> za/zbb/zc -> zxc;
// [64M,192M) zb; then Y0, stats, flag, fp32 params. need ~201 MB.
// ---------------------------------------------------------------------------

typedef unsigned short u16;

#define B_ROWS 32768
#define EPS_BN 0.2f
#define BINV (1.0f / 32768.0f)

__device__ __forceinline__ float bf2f(u16 u) {
    union { unsigned int i; float f; } c;
    c.i = ((unsigned int)u) << 16;
    return c.f;
}
__device__ __forceinline__ u16 f2bf(float f) {
    union { float f; unsigned int i; } c;
    c.f = f;
    unsigned int x = c.i;
    return (u16)((x + 0x7FFFu + ((x >> 16) & 1u)) >> 16);  // RNE
}

// ---------------------------------------------------------------------------
// Detect input dtype. Even-indexed u16s of an fp32 N(0,1) array are random
// mantissa bits (~12% look like plausible bf16 exponents); of a bf16 array
// they are the values themselves (~100% plausible). flag: 1 = bf16, 0 = fp32.
// ---------------------------------------------------------------------------
__global__ void detect_dtype(const u16* __restrict__ x, int* __restrict__ flag) {
    const int lane = threadIdx.x;  // 64 threads
    const u16 v = x[2 * lane];
    const int e = (v >> 7) & 0xFF;
    const bool plausible = (e >= 110 && e <= 140);
    const unsigned long long m = __ballot(plausible);
    if (lane == 0) *flag = (__popcll(m) >= 58) ? 1 : 0;
}

// ---------------------------------------------------------------------------
// Up-convert all param tensors to fp32 staging (reads fp32 or bf16 per flag).
// ---------------------------------------------------------------------------
struct PTab { const void* p[34]; int n[34]; int off[34]; };

__global__ void convert_params(PTab t, float* __restrict__ dst,
                               const int* __restrict__ flag) {
    const int ti = blockIdx.y;
    const int n = t.n[ti];
    float* o = dst + t.off[ti];
    const int isbf = *flag;
    for (int i = blockIdx.x * 256 + threadIdx.x; i < n; i += gridDim.x * 256) {
        o[i] = isbf ? bf2f(((const u16*)t.p[ti])[i]) : ((const float*)t.p[ti])[i];
    }
}

// ---------------------------------------------------------------------------
// Generic fused stage:  Z = relu( norm(X) @ W + bias ),  bf16 Z out,
// plus column sum/sumsq atomics for the NEXT stage's BN.
//   XDYN: X dtype decided at runtime via dtflag (stage A). Else X is bf16.
//   NORM: per-col scale/shift from producer stats (psum/psq) + affine pg/pbe.
//   ROWW: cols < ksplit scaled by Y0[row], cols >= ksplit by 1-Y0[row].
//   Split-K inputs: second half at X + B_ROWS*rs when k0 >= ksplit.
// Tile: 64x64, 256 threads, 4x4 per thread, K-step 16. W/bias/pg/pbe fp32.
// ---------------------------------------------------------------------------
template <bool XDYN, bool NORM, bool ROWW, int K, int N>
__global__ __launch_bounds__(256) void gemm_bn(
    const void* __restrict__ Xv, long xstride, int ksplit, int rs,
    const int* __restrict__ dtflag,
    const float* __restrict__ W, long wstride,
    const float* __restrict__ bias, long bstride,
    u16* __restrict__ Out, long ostride,
    float* __restrict__ gsum, float* __restrict__ gsq, int sstride,
    const float* __restrict__ psum, const float* __restrict__ psq, int pstride,
    const float* __restrict__ pg, const float* __restrict__ pbe, int gmask,
    const float* __restrict__ Y0, int ystride)
{
    const int tid = threadIdx.x;
    const int inst = blockIdx.z;
    const int rowBase = blockIdx.x * 64;
    const int n0 = blockIdx.y * 64;

    __shared__ float sn[NORM ? K : 1];
    __shared__ float tn[NORM ? K : 1];
    __shared__ __align__(16) float Xs[16][68];   // [k][m], padded
    __shared__ __align__(16) float Ws[16][64];   // [k][n]
    __shared__ __align__(16) float red[16][64];

    const float* Wp = W + wstride * inst;
    const float* bp = bias + bstride * inst;
    u16* op = Out + ostride * inst;

    const bool isbf = XDYN ? (*dtflag != 0) : true;

    if (NORM) {
        const float* ps = psum + (long)pstride * inst;
        const float* pq = psq + (long)pstride * inst;
        for (int i = tid; i < K; i += 256) {
            float m = ps[i] * BINV;
            float v = pq[i] * BINV - m * m;
            float s = pg[i & gmask] * rsqrtf(v + EPS_BN);
            sn[i] = s;
            tn[i] = pbe[i & gmask] - m * s;
        }
    }

    float acc[4][4];
#pragma unroll
    for (int i = 0; i < 4; i++)
#pragma unroll
        for (int j = 0; j < 4; j++) acc[i][j] = 0.f;

    const int xr = tid >> 2;        // 0..63 tile row (staging)
    const int xk = (tid & 3) * 4;   // 0,4,8,12 k within chunk (staging)
    const int wk = tid >> 4;        // 0..15 k row (W staging)
    const int wc = (tid & 15) * 4;  // 0..60 col (W staging)
    const int ty = tid >> 4;        // compute row group
    const int tx = tid & 15;        // compute col group

    float yw0 = 0.f, yw1 = 0.f;
    if (ROWW) {
        float y = Y0[(long)ystride * inst + rowBase + xr];
        yw0 = y;
        yw1 = 1.f - y;
    }

    for (int k0 = 0; k0 < K; k0 += 16) {
        __syncthreads();
        float xv[4];
        if (!isbf) {
            const float* s32 = (const float*)Xv + xstride * inst;
            int kc = k0;
            if (k0 >= ksplit) { s32 += (long)B_ROWS * rs; kc -= ksplit; }
            const float4 q = *(const float4*)(s32 + (long)(rowBase + xr) * rs + kc + xk);
            xv[0] = q.x; xv[1] = q.y; xv[2] = q.z; xv[3] = q.w;
        } else {
            const u16* s16 = (const u16*)Xv + xstride * inst;
            int kc = k0;
            if (k0 >= ksplit) { s16 += (long)B_ROWS * rs; kc -= ksplit; }
            const ushort4 q = *(const ushort4*)(s16 + (long)(rowBase + xr) * rs + kc + xk);
            xv[0] = bf2f(q.x); xv[1] = bf2f(q.y); xv[2] = bf2f(q.z); xv[3] = bf2f(q.w);
        }
        if (NORM) {
#pragma unroll
            for (int j = 0; j < 4; j++) xv[j] = xv[j] * sn[k0 + xk + j] + tn[k0 + xk + j];
        }
        if (ROWW) {
            const float w = (k0 < ksplit) ? yw0 : yw1;
#pragma unroll
            for (int j = 0; j < 4; j++) xv[j] *= w;
        }
#pragma unroll
        for (int j = 0; j < 4; j++) Xs[xk + j][xr] = xv[j];

        const float4 wq = *(const float4*)(Wp + (long)(k0 + wk) * N + n0 + wc);
        *(float4*)&Ws[wk][wc] = wq;
        __syncthreads();

#pragma unroll
        for (int k = 0; k < 16; k++) {
            const float4 a = *(const float4*)&Xs[k][ty * 4];
            const float4 b = *(const float4*)&Ws[k][tx * 4];
            const float av[4] = {a.x, a.y, a.z, a.w};
            const float bv[4] = {b.x, b.y, b.z, b.w};
#pragma unroll
            for (int i = 0; i < 4; i++)
#pragma unroll
                for (int j = 0; j < 4; j++) acc[i][j] = fmaf(av[i], bv[j], acc[i][j]);
        }
    }

    // epilogue: bias + relu + bf16 store + column partials
    float colsum[4] = {0.f, 0.f, 0.f, 0.f};
    float colsq[4] = {0.f, 0.f, 0.f, 0.f};
    float bb[4];
#pragma unroll
    for (int j = 0; j < 4; j++) bb[j] = bp[n0 + tx * 4 + j];
#pragma unroll
    for (int i = 0; i < 4; i++) {
        float vv[4];
#pragma unroll
        for (int j = 0; j < 4; j++) {
            float v = fmaxf(acc[i][j] + bb[j], 0.f);
            vv[j] = v;
            colsum[j] += v;
            colsq[j] += v * v;
        }
        ushort4 ob;
        ob.x = f2bf(vv[0]); ob.y = f2bf(vv[1]); ob.z = f2bf(vv[2]); ob.w = f2bf(vv[3]);
        *(ushort4*)(op + (long)(rowBase + ty * 4 + i) * N + n0 + tx * 4) = ob;
    }

    __syncthreads();
    *(float4*)&red[ty][tx * 4] = make_float4(colsum[0], colsum[1], colsum[2], colsum[3]);
    __syncthreads();
    if (tid < 64) {
        float s = 0.f;
#pragma unroll
        for (int t = 0; t < 16; t++) s += red[t][tid];
        atomicAdd(&gsum[(long)sstride * inst + n0 + tid], s);
    }
    __syncthreads();
    *(float4*)&red[ty][tx * 4] = make_float4(colsq[0], colsq[1], colsq[2], colsq[3]);
    __syncthreads();
    if (tid < 64) {
        float s = 0.f;
#pragma unroll
        for (int t = 0; t < 16; t++) s += red[t][tid];
        atomicAdd(&gsq[(long)sstride * inst + n0 + tid], s);
    }
}

// ---------------------------------------------------------------------------
// Gating head: y0 = softmax( bn(zc) @ Wy + by )[...,0]. One wave per (row,k).
// ---------------------------------------------------------------------------
__global__ __launch_bounds__(256) void gate_kernel(
    const u16* __restrict__ zc,
    const float* __restrict__ stFs, const float* __restrict__ stFq,
    const float* __restrict__ g4, const float* __restrict__ be4,
    const float* __restrict__ Wy, const float* __restrict__ by,
    float* __restrict__ Y0)
{
    const int lane = threadIdx.x & 63;
    const int wid = threadIdx.x >> 6;
    const int k = blockIdx.y;
    const int row = blockIdx.x * 4 + wid;

    const float m = stFs[k * 64 + lane] * BINV;
    const float v = stFq[k * 64 + lane] * BINV - m * m;
    const float s = g4[lane] * rsqrtf(v + EPS_BN);
    const float t = be4[lane] - m * s;
    const float x = bf2f(zc[((long)k * B_ROWS + row) * 64 + lane]) * s + t;

    float p0 = x * Wy[k * 128 + lane * 2 + 0];
    float p1 = x * Wy[k * 128 + lane * 2 + 1];
#pragma unroll
    for (int off = 32; off; off >>= 1) {
        p0 += __shfl_xor(p0, off);
        p1 += __shfl_xor(p1, off);
    }
    if (lane == 0) {
        const float l0 = p0 + by[k * 2 + 0];
        const float l1 = p1 + by[k * 2 + 1];
        Y0[(long)k * B_ROWS + row] = 1.f / (1.f + __expf(l1 - l0));
    }
}

// ---------------------------------------------------------------------------
// Output heads: out_k = softmax( bn(zxc[k]) @ Wo_k + bo_k ). Wave per (row,k).
// Output dtype follows the detected input dtype.
// ---------------------------------------------------------------------------
__global__ __launch_bounds__(256) void heads_kernel(
    const u16* __restrict__ zxc,
    const float* __restrict__ stHs, const float* __restrict__ stHq,
    const float* __restrict__ g1, const float* __restrict__ be1,
    const float* __restrict__ Wo1, const float* __restrict__ bo1,
    const float* __restrict__ Wo2, const float* __restrict__ bo2,
    const float* __restrict__ Wo3, const float* __restrict__ bo3,
    const float* __restrict__ Wo4, const float* __restrict__ bo4,
    void* __restrict__ out, const int* __restrict__ dtflag)
{
    const int lane = threadIdx.x & 63;
    const int wid = threadIdx.x >> 6;
    const int k = blockIdx.y;
    const int row = blockIdx.x * 4 + wid;
    const int c0 = lane * 4;

    const ushort4 q = *(const ushort4*)(zxc + ((long)k * B_ROWS + row) * 256 + c0);
    float x[4] = {bf2f(q.x), bf2f(q.y), bf2f(q.z), bf2f(q.w)};
#pragma unroll
    for (int j = 0; j < 4; j++) {
        const int c = c0 + j;
        const float m = stHs[k * 256 + c] * BINV;
        const float v = stHq[k * 256 + c] * BINV - m * m;
        const float s = g1[c] * rsqrtf(v + EPS_BN);
        x[j] = x[j] * s + (be1[c] - m * s);
    }

    const float* Wo; const float* bo; int nk; long obase;
    if (k == 0)      { Wo = Wo1; bo = bo1; nk = 3; obase = 0; }
    else if (k == 1) { Wo = Wo2; bo = bo2; nk = 3; obase = (long)3 * B_ROWS; }
    else if (k == 2) { Wo = Wo3; bo = bo3; nk = 6; obase = (long)6 * B_ROWS; }
    else             { Wo = Wo4; bo = bo4; nk = 4; obase = (long)12 * B_ROWS; }

    float l[6];
#pragma unroll
    for (int j = 0; j < 6; j++) l[j] = 0.f;
#pragma unroll
    for (int j = 0; j < 6; j++) {
        if (j < nk) {
            float p = 0.f;
#pragma unroll
            for (int i = 0; i < 4; i++) p += x[i] * Wo[(c0 + i) * nk + j];
            l[j] = p;
        }
    }
#pragma unroll
    for (int off = 32; off; off >>= 1) {
#pragma unroll
        for (int j = 0; j < 6; j++) l[j] += __shfl_xor(l[j], off);
    }

    if (lane == 0) {
        float mx = -1e30f;
#pragma unroll
        for (int j = 0; j < 6; j++)
            if (j < nk) { l[j] += bo[j]; mx = fmaxf(mx, l[j]); }
        float e[6];
        float se = 0.f;
#pragma unroll
        for (int j = 0; j < 6; j++)
            if (j < nk) { e[j] = __expf(l[j] - mx); se += e[j]; }
        const float inv = 1.f / se;
        if (*dtflag) {
            u16* ob = (u16*)out;
#pragma unroll
            for (int j = 0; j < 6; j++)
                if (j < nk) ob[obase + (long)row * nk + j] = f2bf(e[j] * inv);
        } else {
            float* of = (float*)out;
#pragma unroll
            for (int j = 0; j < 6; j++)
                if (j < nk) of[obase + (long)row * nk + j] = e[j] * inv;
        }
    }
}

// Diagnostic fallback if workspace is too small: repeating 0x3E80 pattern
// reads as ~0.25 under both bf16 and fp32 interpretation.
__global__ void fill_sentinel(u16* out, int n) {
    int i = blockIdx.x * 256 + threadIdx.x;
    if (i < n) out[i] = 0x3E80;
}

// ---------------------------------------------------------------------------
extern "C" void kernel_launch(void* const* d_in, const int* in_sizes, int n_in,
                              void* d_out, int out_size, void* d_ws, size_t ws_size,
                              hipStream_t stream)
{
    const long B = B_ROWS;
    char* ws = (char*)d_ws;
    const size_t MB = 1024 * 1024;

    // Lifetime-aliased layout
    u16* z1  = (u16*)(ws);                      // [2][B][256]
    u16* z2  = (u16*)(ws + 32 * MB);            // [2][B][256]
    u16* za  = (u16*)(ws);                      // [4][B][128]
    u16* zbb = (u16*)(ws + 32 * MB);            // [4][B][64]
    u16* zc  = (u16*)(ws + 48 * MB);            // [4][B][64]
    u16* zxc = (u16*)(ws);                      // [4][B][256]
    u16* zb  = (u16*)(ws + 64 * MB);            // [4][2][B][256]
    float* Y0 = (float*)(ws + 192 * MB);        // [4][B]   (512 KB)
    float* stats = (float*)(ws + 192 * MB + 512 * 1024);   // 40 KB
    int* dtflag = (int*)(ws + 192 * MB + 576 * 1024);
    float* Pst = (float*)(ws + 193 * MB);       // fp32 params (~6.3 MB)

    // param staging offsets (d_in[2..35])
    PTab tab;
    int acc = 0;
    for (int i = 0; i < 34; i++) {
        tab.p[i] = d_in[i + 2];
        tab.n[i] = in_sizes[i + 2];
        tab.off[i] = acc;
        acc += in_sizes[i + 2];
    }
    const size_t need = 193 * MB + (size_t)acc * 4 + 1024;
    if (need > ws_size) {
        fill_sentinel<<<(out_size + 255) / 256, 256, 0, stream>>>((u16*)d_out, out_size);
        return;
    }
    auto PF = [&](int idx) { return Pst + tab.off[idx - 2]; };

    float* stAs = stats;        float* stAq = stAs + 512;   // [2][256]
    float* stBs = stAq + 512;   float* stBq = stBs + 512;   // [2][256]
    float* stCs = stBq + 512;   float* stCq = stCs + 2048;  // [k][s][256]
    float* stDs = stCq + 2048;  float* stDq = stDs + 512;   // [4][128]
    float* stEs = stDq + 512;   float* stEq = stEs + 256;   // [4][64]
    float* stFs = stEq + 256;   float* stFq = stFs + 256;   // [4][64]
    float* stHs = stFq + 256;   float* stHq = stHs + 1024;  // [4][256]

    hipMemsetAsync(stats, 0, 10240 * 4, stream);
    detect_dtype<<<1, 64, 0, stream>>>((const u16*)d_in[0], dtflag);
    convert_params<<<dim3(64, 34), 256, 0, stream>>>(tab, Pst, dtflag);

    const dim3 blk(256);

    // Stage A: trunk layer 1, both streams (dynamic-dtype input, no norm)
    gemm_bn<true, false, false, 512, 256><<<dim3(512, 4, 1), blk, 0, stream>>>(
        d_in[0], 0, 512, 512, dtflag, PF(2), 0, PF(3), 0, z1, 0,
        stAs, stAq, 0, nullptr, nullptr, 0, nullptr, nullptr, 0, nullptr, 0);
    gemm_bn<true, false, false, 512, 256><<<dim3(512, 4, 1), blk, 0, stream>>>(
        d_in[1], 0, 512, 512, dtflag, PF(2), 0, PF(3), 0, z1 + B * 256, 0,
        stAs + 256, stAq + 256, 0, nullptr, nullptr, 0, nullptr, nullptr, 0, nullptr, 0);

    // Stage B: trunk layer 2 (input norm: stA + g1/be1)
    gemm_bn<false, true, false, 256, 256><<<dim3(512, 4, 2), blk, 0, stream>>>(
        z1, B * 256, 256, 256, nullptr, PF(4), 0, PF(5), 0, z2, B * 256,
        stBs, stBq, 256, stAs, stAq, 256, PF(6), PF(7), 255, nullptr, 0);

    // Stage C: 4 branch projections per stream (input norm: stB + g2/be2)
    for (int s = 0; s < 2; s++) {
        gemm_bn<false, true, false, 256, 256><<<dim3(512, 4, 4), blk, 0, stream>>>(
            z2 + (long)s * B * 256, 0, 256, 256, nullptr,
            s ? PF(16) : PF(14), 256 * 256, s ? PF(17) : PF(15), 256,
            zb + (long)s * B * 256, 2l * B * 256,
            stCs + s * 256, stCq + s * 256, 512,
            stBs + s * 256, stBq + s * 256, 0, PF(8), PF(9), 255, nullptr, 0);
    }

    // Stage D: gating layer a; xcat = [bn(zb[k,0]) | bn(zb[k,1])] via split-K
    gemm_bn<false, true, false, 512, 128><<<dim3(512, 2, 4), blk, 0, stream>>>(
        zb, 2l * B * 256, 256, 256, nullptr, PF(18), 512 * 128, PF(19), 128,
        za, B * 128,
        stDs, stDq, 128, stCs, stCq, 512, PF(6), PF(7), 255, nullptr, 0);

    // Stage E: gating layer b (norm: stD + g3/be3)
    gemm_bn<false, true, false, 128, 64><<<dim3(512, 1, 4), blk, 0, stream>>>(
        za, B * 128, 128, 128, nullptr, PF(20), 128 * 64, PF(21), 64,
        zbb, B * 64,
        stEs, stEq, 64, stDs, stDq, 128, PF(10), PF(11), 127, nullptr, 0);

    // Stage F: gating layer c (norm: stE + g4/be4)
    gemm_bn<false, true, false, 64, 64><<<dim3(512, 1, 4), blk, 0, stream>>>(
        zbb, B * 64, 64, 64, nullptr, PF(22), 64 * 64, PF(23), 64,
        zc, B * 64,
        stFs, stFq, 64, stEs, stEq, 64, PF(12), PF(13), 63, nullptr, 0);

    // Gate: y0 per (k,row)
    gate_kernel<<<dim3(B_ROWS / 4, 4), blk, 0, stream>>>(
        zc, stFs, stFq, PF(12), PF(13), PF(24), PF(25), Y0);

    // Stage H: combine. xw never materialized: y0/y1 folded into load.
    gemm_bn<false, true, true, 512, 256><<<dim3(512, 4, 4), blk, 0, stream>>>(
        zb, 2l * B * 256, 256, 256, nullptr, PF(26), 512 * 256, PF(27), 256,
        zxc, B * 256,
        stHs, stHq, 256, stCs, stCq, 512, PF(6), PF(7), 255, Y0, B_ROWS);

    // Output heads + softmax (dtype-dual store)
    heads_kernel<<<dim3(B_ROWS / 4, 4), blk, 0, stream>>>(
        zxc, stHs, stHq, PF(6), PF(7), PF(28), PF(29), PF(30), PF(31),
        PF(32), PF(33), PF(34), PF(35), d_out, dtflag);
}

// Round 4
// 806.370 us; speedup vs baseline: 2.4079x; 2.4079x over previous
//
#include <hip/hip_runtime.h>
#include <hip/hip_bf16.h>

// ---------------------------------------------------------------------------
// CombineMultiOutputModelWeightedConcat — MFMA round.
// bn(x)@W = x@(diag(s)W) + (t·W + bias): per-stage prep_w folds BN into a
// transposed prescaled fp16 weight buffer Wt[n][k] + bias terms, so the MFMA
// GEMM consumes raw fp16 activations. Combine stage: out = y0*(acc0+T0) +
// y1*(acc1+T1) + bias via two accumulator banks (exact, no xw buffer).
// fp16 intermediates (was bf16): lower error + same MFMA rate.
// E/F (3% of FLOP) stay on the old VALU kernel. Dtype-agnostic I/O kept.
// ---------------------------------------------------------------------------

typedef unsigned short u16;
typedef _Float16 f16x8 __attribute__((ext_vector_type(8)));
typedef float f32x4 __attribute__((ext_vector_type(4)));

#define B_ROWS 32768
#define EPS_BN 0.2f
#define BINV (1.0f / 32768.0f)

__device__ __forceinline__ float bf2f(u16 u) {
    union { unsigned int i; float f; } c;
    c.i = ((unsigned int)u) << 16;
    return c.f;
}
__device__ __forceinline__ u16 f2bf(float f) {
    union { float f; unsigned int i; } c;
    c.f = f;
    unsigned int x = c.i;
    return (u16)((x + 0x7FFFu + ((x >> 16) & 1u)) >> 16);
}
__device__ __forceinline__ float h2f(u16 u) {
    _Float16 h;
    __builtin_memcpy(&h, &u, 2);
    return (float)h;
}
__device__ __forceinline__ u16 f2h(float f) {
    _Float16 h = (_Float16)f;
    u16 u;
    __builtin_memcpy(&u, &h, 2);
    return u;
}
__device__ __forceinline__ float ldp(const void* p, long i, int flag) {
    return flag ? bf2f(((const u16*)p)[i]) : ((const float*)p)[i];
}

// --------------------------------------------------------------------------
__global__ void detect_dtype(const u16* __restrict__ x, int* __restrict__ flag) {
    const int lane = threadIdx.x;  // 64 threads
    const u16 v = x[2 * lane];
    const int e = (v >> 7) & 0xFF;
    const bool plausible = (e >= 110 && e <= 140);
    const unsigned long long m = __ballot(plausible);
    if (lane == 0) *flag = (__popcll(m) >= 58) ? 1 : 0;
}

struct PTab { const void* p[20]; int n[20]; int off[20]; };

__global__ void convert_params(PTab t, float* __restrict__ dst,
                               const int* __restrict__ flag) {
    const int ti = blockIdx.y;
    const int n = t.n[ti];
    float* o = dst + t.off[ti];
    const int isbf = *flag;
    for (int i = blockIdx.x * 256 + threadIdx.x; i < n; i += gridDim.x * 256)
        o[i] = ldp(t.p[ti], i, isbf);
}

// ---------------------------------------------------------------------------
// prep_w: Wt[inst][n][k] = f16(s_k * W[k][n]);  T0/T1[n] = sum_{k<,>=khalf}
// t_k*W[k][n];  biasP = bias;  bsum = bias+T0+T1.  s,t from producer stats.
// grid = (N, numInst), 256 threads.
// ---------------------------------------------------------------------------
__global__ __launch_bounds__(256) void prep_w(
    const void* __restrict__ W, long wstride,
    const void* __restrict__ bias, long bstride,
    const float* __restrict__ psum, const float* __restrict__ psq, int pstride,
    const void* __restrict__ pg, const void* __restrict__ pbe, int gmask,
    const int* __restrict__ dtflag,
    u16* __restrict__ Wt, long wtstride,
    float* __restrict__ biasP, float* __restrict__ T0o,
    float* __restrict__ T1o, float* __restrict__ bsum, long bost,
    int K, int khalf)
{
    const int tid = threadIdx.x;
    const int n = blockIdx.x;
    const int N = gridDim.x;
    const int inst = blockIdx.y;
    const int flag = *dtflag;
    __shared__ float sn[512], tn[512];
    __shared__ float r0[4], r1[4];

    for (int i = tid; i < K; i += 256) {
        float s = 1.f, t = 0.f;
        if (psum) {
            float m = psum[(long)pstride * inst + i] * BINV;
            float v = psq[(long)pstride * inst + i] * BINV - m * m;
            float g = ldp(pg, i & gmask, flag);
            float b = ldp(pbe, i & gmask, flag);
            s = g * rsqrtf(v + EPS_BN);
            t = b - m * s;
        }
        sn[i] = s; tn[i] = t;
    }
    __syncthreads();
    float p0 = 0.f, p1 = 0.f;
    for (int k = tid; k < K; k += 256) {
        float wv = ldp(W, wstride * inst + (long)k * N + n, flag);
        Wt[wtstride * inst + (long)n * K + k] = f2h(sn[k] * wv);
        float tw = tn[k] * wv;
        if (k < khalf) p0 += tw; else p1 += tw;
    }
#pragma unroll
    for (int off = 32; off; off >>= 1) {
        p0 += __shfl_xor(p0, off);
        p1 += __shfl_xor(p1, off);
    }
    const int lane = tid & 63, wid = tid >> 6;
    if (lane == 0) { r0[wid] = p0; r1[wid] = p1; }
    __syncthreads();
    if (tid == 0) {
        float t0 = r0[0] + r0[1] + r0[2] + r0[3];
        float t1 = r1[0] + r1[1] + r1[2] + r1[3];
        float bp = ldp(bias, bstride * inst + n, flag);
        long o = bost * inst + n;
        biasP[o] = bp; T0o[o] = t0; T1o[o] = t1; bsum[o] = bp + t0 + t1;
    }
}

// ---------------------------------------------------------------------------
// MFMA GEMM: 128x128 tile, 4 waves (2x2 of 64x64), 16x16x32 f16, BK=64.
// LDS k-contiguous, XOR-swizzled chunk-of-8-halves layout (b128 frag reads,
// <=2-way bank aliasing). Epilogue: bias(+gate-weights)+relu, fp16 store,
// column sum/sumsq atomics.
// ---------------------------------------------------------------------------
#define KSTEP(ACC, KT_)                                                       \
  {                                                                           \
    __syncthreads();                                                          \
    _Pragma("unroll")                                                         \
    for (int p = 0; p < 4; ++p) {                                             \
      int s = p * 256 + tid;                                                  \
      int m = s >> 3, cp = s & 7;                                             \
      int c = cp ^ (m & 7);                                                   \
      int kk = (KT_) * 64 + c * 8;                                            \
      if (XSTAGE) {                                                           \
        if (xf32) {                                                           \
          const float* g = (const float*)xb + (long)(rowBase + m) * ldx + kk; \
          float4 u = *(const float4*)g;                                       \
          float4 u2 = *(const float4*)(g + 4);                                \
          f16x8 h;                                                            \
          h[0] = (_Float16)u.x;  h[1] = (_Float16)u.y;                        \
          h[2] = (_Float16)u.z;  h[3] = (_Float16)u.w;                        \
          h[4] = (_Float16)u2.x; h[5] = (_Float16)u2.y;                       \
          h[6] = (_Float16)u2.z; h[7] = (_Float16)u2.w;                       \
          *(f16x8*)&As[s * 8] = h;                                            \
        } else {                                                              \
          const u16* g = (const u16*)xb + (long)(rowBase + m) * ldx + kk;     \
          uint4 v = *(const uint4*)g;                                         \
          const u16* pv = (const u16*)&v;                                     \
          f16x8 h;                                                            \
          _Pragma("unroll")                                                   \
          for (int j = 0; j < 8; ++j) h[j] = (_Float16)bf2f(pv[j]);           \
          *(f16x8*)&As[s * 8] = h;                                            \
        }                                                                     \
      } else {                                                                \
        const u16* xbase = (const u16*)xb;                                    \
        int kkr = kk;                                                         \
        if (kk >= ksplit) { xbase += ksecond; kkr -= ksplit; }                \
        uint4 v = *(const uint4*)(xbase + (long)(rowBase + m) * ldx + kkr);   \
        *(uint4*)&As[s * 8] = v;                                              \
      }                                                                       \
      uint4 wvv = *(const uint4*)(wtp + (long)(n0 + m) * K + (KT_) * 64 + c * 8); \
      *(uint4*)&Bs[s * 8] = wvv;                                              \
    }                                                                         \
    __syncthreads();                                                          \
    _Pragma("unroll")                                                         \
    for (int q = 0; q < 2; ++q) {                                             \
      f16x8 af[4], bfr[4];                                                    \
      _Pragma("unroll")                                                       \
      for (int mi = 0; mi < 4; ++mi) {                                        \
        int mm = wm * 64 + mi * 16 + fm;                                      \
        int cc = q * 4 + quad;                                                \
        af[mi] = *(const f16x8*)&As[(mm * 8 + (cc ^ (mm & 7))) * 8];          \
      }                                                                       \
      _Pragma("unroll")                                                       \
      for (int ni = 0; ni < 4; ++ni) {                                        \
        int nn = wn * 64 + ni * 16 + fm;                                      \
        int cc = q * 4 + quad;                                                \
        bfr[ni] = *(const f16x8*)&Bs[(nn * 8 + (cc ^ (nn & 7))) * 8];         \
      }                                                                       \
      _Pragma("unroll")                                                       \
      for (int mi = 0; mi < 4; ++mi)                                          \
        _Pragma("unroll")                                                     \
        for (int ni = 0; ni < 4; ++ni)                                        \
          ACC[mi][ni] = __builtin_amdgcn_mfma_f32_16x16x32_f16(               \
              af[mi], bfr[ni], ACC[mi][ni], 0, 0, 0);                         \
    }                                                                         \
  }

template <bool XSTAGE, bool ROWW, int K>
__global__ __launch_bounds__(256) void gemm_mfma(
    const void* __restrict__ X, const void* __restrict__ X2,
    long xstride, int ximask, int ldx, int ksplit, long ksecond,
    const int* __restrict__ dtflag,
    const u16* __restrict__ Wt, long wtstride,
    const float* __restrict__ biasP, const float* __restrict__ T0,
    const float* __restrict__ T1, const float* __restrict__ bsum, int bN,
    u16* __restrict__ Out, long ostride, int ldout,
    float* __restrict__ gsum, float* __restrict__ gsq, int sstride,
    const float* __restrict__ Y0v)
{
    const int tid = threadIdx.x;
    const int inst = blockIdx.z;
    const int rowBase = blockIdx.x * 128;
    const int n0 = blockIdx.y * 128;
    const int lane = tid & 63;
    const int wid = tid >> 6;
    const int wm = wid >> 1, wn = wid & 1;
    const int fm = lane & 15, quad = lane >> 4;

    __shared__ __align__(16) u16 As[8192];   // 128 rows x 8 chunks x 8 halves
    __shared__ __align__(16) u16 Bs[8192];
    __shared__ float redS[2][128], redQ[2][128];

    const bool xf32 = XSTAGE && (*dtflag == 0);
    const char* xb;
    if (XSTAGE) xb = (const char*)(inst == 0 ? X : X2);
    else        xb = (const char*)X + 2l * xstride * (inst & ximask);
    const u16* wtp = Wt + wtstride * inst;
    u16* op = Out + ostride * inst;

    f32x4 acc0[4][4], acc1[4][4];
#pragma unroll
    for (int i = 0; i < 4; ++i)
#pragma unroll
        for (int j = 0; j < 4; ++j) {
            acc0[i][j] = (f32x4){0.f, 0.f, 0.f, 0.f};
            if (ROWW) acc1[i][j] = (f32x4){0.f, 0.f, 0.f, 0.f};
        }

    constexpr int KT = K / 64;
    constexpr int KT1 = ROWW ? 4 : KT;   // ROWW: bank split at k=256
    for (int kt = 0; kt < KT1; ++kt) KSTEP(acc0, kt)
    if constexpr (ROWW) {
        for (int kt = KT1; kt < KT; ++kt) KSTEP(acc1, kt)
    }

    __syncthreads();

    float yv[16];
    if constexpr (ROWW) {
        const float* yp = Y0v + (long)inst * B_ROWS;
#pragma unroll
        for (int mi = 0; mi < 4; ++mi)
#pragma unroll
            for (int r = 0; r < 4; ++r)
                yv[mi * 4 + r] = yp[rowBase + wm * 64 + mi * 16 + quad * 4 + r];
    }

#pragma unroll
    for (int ni = 0; ni < 4; ++ni) {
        const int nc = wn * 64 + ni * 16 + fm;
        const int n = n0 + nc;
        float bS = 0.f, bP = 0.f, t0v = 0.f, t1v = 0.f;
        if constexpr (ROWW) {
            bP = biasP[(long)inst * bN + n];
            t0v = T0[(long)inst * bN + n];
            t1v = T1[(long)inst * bN + n];
        } else {
            bS = bsum[(long)inst * bN + n];
        }
        float s = 0.f, qq = 0.f;
#pragma unroll
        for (int mi = 0; mi < 4; ++mi) {
            const int rbase = rowBase + wm * 64 + mi * 16 + quad * 4;
#pragma unroll
            for (int r = 0; r < 4; ++r) {
                float v;
                if constexpr (ROWW) {
                    const float y = yv[mi * 4 + r];
                    v = y * (acc0[mi][ni][r] + t0v) +
                        (1.f - y) * (acc1[mi][ni][r] + t1v) + bP;
                } else {
                    v = acc0[mi][ni][r] + bS;
                }
                v = fmaxf(v, 0.f);
                s += v; qq += v * v;
                op[(long)(rbase + r) * ldout + n] = f2h(v);
            }
        }
        s += __shfl_xor(s, 16);  s += __shfl_xor(s, 32);
        qq += __shfl_xor(qq, 16); qq += __shfl_xor(qq, 32);
        if (quad == 0) { redS[wm][nc] = s; redQ[wm][nc] = qq; }
    }
    __syncthreads();
    if (tid < 128) {
        atomicAdd(&gsum[(long)inst * sstride + n0 + tid], redS[0][tid] + redS[1][tid]);
        atomicAdd(&gsq [(long)inst * sstride + n0 + tid], redQ[0][tid] + redQ[1][tid]);
    }
}

// ---------------------------------------------------------------------------
// Old VALU kernel for the small E/F stages (fp16 activations, fp32 weights).
// ---------------------------------------------------------------------------
template <bool NORM, int K, int N>
__global__ __launch_bounds__(256) void gemm_bn(
    const u16* __restrict__ X, long xstride, int rs,
    const float* __restrict__ W, long wstride,
    const float* __restrict__ bias, long bstride,
    u16* __restrict__ Out, long ostride,
    float* __restrict__ gsum, float* __restrict__ gsq, int sstride,
    const float* __restrict__ psum, const float* __restrict__ psq, int pstride,
    const float* __restrict__ pg, const float* __restrict__ pbe, int gmask)
{
    const int tid = threadIdx.x;
    const int inst = blockIdx.z;
    const int rowBase = blockIdx.x * 64;
    const int n0 = blockIdx.y * 64;

    __shared__ float sn[NORM ? K : 1];
    __shared__ float tn[NORM ? K : 1];
    __shared__ __align__(16) float Xs[16][68];
    __shared__ __align__(16) float Ws[16][64];
    __shared__ __align__(16) float red[16][64];

    const float* Wp = W + wstride * inst;
    const float* bp = bias + bstride * inst;
    u16* op = Out + ostride * inst;

    if (NORM) {
        const float* ps = psum + (long)pstride * inst;
        const float* pq = psq + (long)pstride * inst;
        for (int i = tid; i < K; i += 256) {
            float m = ps[i] * BINV;
            float v = pq[i] * BINV - m * m;
            float s = pg[i & gmask] * rsqrtf(v + EPS_BN);
            sn[i] = s;
            tn[i] = pbe[i & gmask] - m * s;
        }
    }

    float acc[4][4];
#pragma unroll
    for (int i = 0; i < 4; i++)
#pragma unroll
        for (int j = 0; j < 4; j++) acc[i][j] = 0.f;

    const int xr = tid >> 2;
    const int xk = (tid & 3) * 4;
    const int wk = tid >> 4;
    const int wc = (tid & 15) * 4;
    const int ty = tid >> 4;
    const int tx = tid & 15;

    const u16* Xb = X + xstride * inst;

    for (int k0 = 0; k0 < K; k0 += 16) {
        __syncthreads();
        const ushort4 q = *(const ushort4*)(Xb + (long)(rowBase + xr) * rs + k0 + xk);
        float xv[4] = {h2f(q.x), h2f(q.y), h2f(q.z), h2f(q.w)};
        if (NORM) {
#pragma unroll
            for (int j = 0; j < 4; j++) xv[j] = xv[j] * sn[k0 + xk + j] + tn[k0 + xk + j];
        }
#pragma unroll
        for (int j = 0; j < 4; j++) Xs[xk + j][xr] = xv[j];

        const float4 wq = *(const float4*)(Wp + (long)(k0 + wk) * N + n0 + wc);
        *(float4*)&Ws[wk][wc] = wq;
        __syncthreads();

#pragma unroll
        for (int k = 0; k < 16; k++) {
            const float4 a = *(const float4*)&Xs[k][ty * 4];
            const float4 b = *(const float4*)&Ws[k][tx * 4];
            const float av[4] = {a.x, a.y, a.z, a.w};
            const float bv[4] = {b.x, b.y, b.z, b.w};
#pragma unroll
            for (int i = 0; i < 4; i++)
#pragma unroll
                for (int j = 0; j < 4; j++) acc[i][j] = fmaf(av[i], bv[j], acc[i][j]);
        }
    }

    float colsum[4] = {0.f, 0.f, 0.f, 0.f};
    float colsq[4] = {0.f, 0.f, 0.f, 0.f};
    float bb[4];
#pragma unroll
    for (int j = 0; j < 4; j++) bb[j] = bp[n0 + tx * 4 + j];
#pragma unroll
    for (int i = 0; i < 4; i++) {
        float vv[4];
#pragma unroll
        for (int j = 0; j < 4; j++) {
            float v = fmaxf(acc[i][j] + bb[j], 0.f);
            vv[j] = v;
            colsum[j] += v;
            colsq[j] += v * v;
        }
        ushort4 ob;
        ob.x = f2h(vv[0]); ob.y = f2h(vv[1]); ob.z = f2h(vv[2]); ob.w = f2h(vv[3]);
        *(ushort4*)(op + (long)(rowBase + ty * 4 + i) * N + n0 + tx * 4) = ob;
    }

    __syncthreads();
    *(float4*)&red[ty][tx * 4] = make_float4(colsum[0], colsum[1], colsum[2], colsum[3]);
    __syncthreads();
    if (tid < 64) {
        float s = 0.f;
#pragma unroll
        for (int t = 0; t < 16; t++) s += red[t][tid];
        atomicAdd(&gsum[(long)sstride * inst + n0 + tid], s);
    }
    __syncthreads();
    *(float4*)&red[ty][tx * 4] = make_float4(colsq[0], colsq[1], colsq[2], colsq[3]);
    __syncthreads();
    if (tid < 64) {
        float s = 0.f;
#pragma unroll
        for (int t = 0; t < 16; t++) s += red[t][tid];
        atomicAdd(&gsq[(long)sstride * inst + n0 + tid], s);
    }
}

// ---------------------------------------------------------------------------
__global__ __launch_bounds__(256) void gate_kernel(
    const u16* __restrict__ zc,
    const float* __restrict__ stFs, const float* __restrict__ stFq,
    const float* __restrict__ g4, const float* __restrict__ be4,
    const float* __restrict__ Wy, const float* __restrict__ by,
    float* __restrict__ Y0)
{
    const int lane = threadIdx.x & 63;
    const int wid = threadIdx.x >> 6;
    const int k = blockIdx.y;
    const int row = blockIdx.x * 4 + wid;

    const float m = stFs[k * 64 + lane] * BINV;
    const float v = stFq[k * 64 + lane] * BINV - m * m;
    const float s = g4[lane] * rsqrtf(v + EPS_BN);
    const float t = be4[lane] - m * s;
    const float x = h2f(zc[((long)k * B_ROWS + row) * 64 + lane]) * s + t;

    float p0 = x * Wy[k * 128 + lane * 2 + 0];
    float p1 = x * Wy[k * 128 + lane * 2 + 1];
#pragma unroll
    for (int off = 32; off; off >>= 1) {
        p0 += __shfl_xor(p0, off);
        p1 += __shfl_xor(p1, off);
    }
    if (lane == 0) {
        const float l0 = p0 + by[k * 2 + 0];
        const float l1 = p1 + by[k * 2 + 1];
        Y0[(long)k * B_ROWS + row] = 1.f / (1.f + __expf(l1 - l0));
    }
}

// ---------------------------------------------------------------------------
__global__ __launch_bounds__(256) void heads_kernel(
    const u16* __restrict__ zxc,
    const float* __restrict__ stHs, const float* __restrict__ stHq,
    const float* __restrict__ g1, const float* __restrict__ be1,
    const float* __restrict__ Wo1, const float* __restrict__ bo1,
    const float* __restrict__ Wo2, const float* __restrict__ bo2,
    const float* __restrict__ Wo3, const float* __restrict__ bo3,
    const float* __restrict__ Wo4, const float* __restrict__ bo4,
    void* __restrict__ out, const int* __restrict__ dtflag)
{
    const int lane = threadIdx.x & 63;
    const int wid = threadIdx.x >> 6;
    const int k = blockIdx.y;
    const int row = blockIdx.x * 4 + wid;
    const int c0 = lane * 4;

    const ushort4 q = *(const ushort4*)(zxc + ((long)k * B_ROWS + row) * 256 + c0);
    float x[4] = {h2f(q.x), h2f(q.y), h2f(q.z), h2f(q.w)};
#pragma unroll
    for (int j = 0; j < 4; j++) {
        const int c = c0 + j;
        const float m = stHs[k * 256 + c] * BINV;
        const float v = stHq[k * 256 + c] * BINV - m * m;
        const float s = g1[c] * rsqrtf(v + EPS_BN);
        x[j] = x[j] * s + (be1[c] - m * s);
    }

    const float* Wo; const float* bo; int nk; long obase;
    if (k == 0)      { Wo = Wo1; bo = bo1; nk = 3; obase = 0; }
    else if (k == 1) { Wo = Wo2; bo = bo2; nk = 3; obase = (long)3 * B_ROWS; }
    else if (k == 2) { Wo = Wo3; bo = bo3; nk = 6; obase = (long)6 * B_ROWS; }
    else             { Wo = Wo4; bo = bo4; nk = 4; obase = (long)12 * B_ROWS; }

    float l[6];
#pragma unroll
    for (int j = 0; j < 6; j++) l[j] = 0.f;
#pragma unroll
    for (int j = 0; j < 6; j++) {
        if (j < nk) {
            float p = 0.f;
#pragma unroll
            for (int i = 0; i < 4; i++) p += x[i] * Wo[(c0 + i) * nk + j];
            l[j] = p;
        }
    }
#pragma unroll
    for (int off = 32; off; off >>= 1) {
#pragma unroll
        for (int j = 0; j < 6; j++) l[j] += __shfl_xor(l[j], off);
    }

    if (lane == 0) {
        float mx = -1e30f;
#pragma unroll
        for (int j = 0; j < 6; j++)
            if (j < nk) { l[j] += bo[j]; mx = fmaxf(mx, l[j]); }
        float e[6];
        float se = 0.f;
#pragma unroll
        for (int j = 0; j < 6; j++)
            if (j < nk) { e[j] = __expf(l[j] - mx); se += e[j]; }
        const float inv = 1.f / se;
        if (*dtflag) {
            u16* ob = (u16*)out;
#pragma unroll
            for (int j = 0; j < 6; j++)
                if (j < nk) ob[obase + (long)row * nk + j] = f2bf(e[j] * inv);
        } else {
            float* of = (float*)out;
#pragma unroll
            for (int j = 0; j < 6; j++)
                if (j < nk) of[obase + (long)row * nk + j] = e[j] * inv;
        }
    }
}

__global__ void fill_sentinel(u16* out, int n) {
    int i = blockIdx.x * 256 + threadIdx.x;
    if (i < n) out[i] = 0x3E80;
}

// ---------------------------------------------------------------------------
extern "C" void kernel_launch(void* const* d_in, const int* in_sizes, int n_in,
                              void* d_out, int out_size, void* d_ws, size_t ws_size,
                              hipStream_t stream)
{
    const long B = B_ROWS;
    char* ws = (char*)d_ws;
    const size_t MB = 1024 * 1024;

    // Lifetime-aliased activation layout (fp16 now, same sizes)
    u16* z1  = (u16*)(ws);                      // [2][B][256]
    u16* z2  = (u16*)(ws + 32 * MB);            // [2][B][256]
    u16* za  = (u16*)(ws);                      // [4][B][128]
    u16* zbb = (u16*)(ws + 32 * MB);            // [4][B][64]
    u16* zc  = (u16*)(ws + 48 * MB);            // [4][B][64]
    u16* zxc = (u16*)(ws);                      // [4][B][256]
    u16* zb  = (u16*)(ws + 64 * MB);            // [k][s][B][256]
    float* Y0 = (float*)(ws + 192 * MB);                   // 512 KB
    float* stats = (float*)(ws + 192 * MB + 512 * 1024);   // 40 KB
    int* dtflag = (int*)(ws + 192 * MB + 576 * 1024);
    float* Pst = (float*)(ws + 192 * MB + 640 * 1024);     // small fp32 params

    // Wt region (fp16, prescaled+transposed weights)
    u16* WtA = (u16*)(ws + 193 * MB);                 // [256][512]
    u16* WtB = WtA + 131072;                          // [2][256][256]
    u16* WtC = WtB + 131072;                          // [8][256][256]
    u16* WtD = WtC + 524288;                          // [4][128][512]
    u16* WtH = WtD + 262144;                          // [4][256][512]
    float* biasArea = (float*)(ws + 197 * MB);        // 18432 floats
    float* bA = biasArea;        // cnt 512 (2 inst x 256)
    float* bB = bA + 2048;       // cnt 512
    float* bC = bB + 2048;       // cnt 2048 (8 x 256)
    float* bD = bC + 8192;       // cnt 512 (4 x 128)
    float* bH = bD + 2048;       // cnt 1024 (4 x 256)

    // fp32 param staging: only non-dual-dtype consumers (E/F/gate/heads)
    const int cIdx[20] = {6,7,10,11,12,13,20,21,22,23,24,25,28,29,30,31,32,33,34,35};
    PTab tab;
    int mapOff[36];
    int acc = 0;
    for (int i = 0; i < 20; i++) {
        tab.p[i] = d_in[cIdx[i]];
        tab.n[i] = in_sizes[cIdx[i]];
        tab.off[i] = acc;
        mapOff[cIdx[i]] = acc;
        acc += in_sizes[cIdx[i]];
    }
    const size_t need = 197 * MB + 18432 * 4 + 4096;
    if (need > ws_size || (size_t)acc * 4 > 384 * 1024) {
        fill_sentinel<<<(out_size + 255) / 256, 256, 0, stream>>>((u16*)d_out, out_size);
        return;
    }
    auto PF = [&](int idx) { return Pst + mapOff[idx]; };

    float* stAs = stats;        float* stAq = stAs + 512;   // [2][256]
    float* stBs = stAq + 512;   float* stBq = stBs + 512;   // [2][256]
    float* stCs = stBq + 512;   float* stCq = stCs + 2048;  // [k][s][256]
    float* stDs = stCq + 2048;  float* stDq = stDs + 512;   // [4][128]
    float* stEs = stDq + 512;   float* stEq = stEs + 256;   // [4][64]
    float* stFs = stEq + 256;   float* stFq = stFs + 256;   // [4][64]
    float* stHs = stFq + 256;   float* stHq = stHs + 1024;  // [4][256]

    hipMemsetAsync(stats, 0, 10240 * 4, stream);
    detect_dtype<<<1, 64, 0, stream>>>((const u16*)d_in[0], dtflag);
    convert_params<<<dim3(32, 20), 256, 0, stream>>>(tab, Pst, dtflag);

    const dim3 blk(256);
    const int BIGK = 1 << 29;  // "never split"

    // ---- Stage A: trunk L1 (dual-dtype X, no norm) -----------------------
    prep_w<<<dim3(256, 2), blk, 0, stream>>>(
        d_in[2], 0, d_in[3], 0, nullptr, nullptr, 0, nullptr, nullptr, 0,
        dtflag, WtA, 0, bA, bA + 512, bA + 1024, bA + 1536, 256, 512, 512);
    gemm_mfma<true, false, 512><<<dim3(256, 2, 2), blk, 0, stream>>>(
        d_in[0], d_in[1], 0, 0, 512, BIGK, 0, dtflag, WtA, 0,
        bA, bA + 512, bA + 1024, bA + 1536, 256,
        z1, B * 256, 256, stAs, stAq, 256, nullptr);

    // ---- Stage B: trunk L2 (norm stA + g1/be1 folded into WtB) -----------
    prep_w<<<dim3(256, 2), blk, 0, stream>>>(
        d_in[4], 0, d_in[5], 0, stAs, stAq, 256, d_in[6], d_in[7], 255,
        dtflag, WtB, 65536, bB, bB + 512, bB + 1024, bB + 1536, 256, 256, 256);
    gemm_mfma<false, false, 256><<<dim3(256, 2, 2), blk, 0, stream>>>(
        z1, nullptr, B * 256, 3, 256, BIGK, 0, dtflag, WtB, 65536,
        bB, bB + 512, bB + 1024, bB + 1536, 256,
        z2, B * 256, 256, stBs, stBq, 256, nullptr);

    // ---- Stage C: 8 branch projections (norm stB + g2/be2) ---------------
    for (int s = 0; s < 2; s++) {
        prep_w<<<dim3(256, 4), blk, 0, stream>>>(
            d_in[s ? 16 : 14], 65536, d_in[s ? 17 : 15], 256,
            stBs + s * 256, stBq + s * 256, 0, d_in[8], d_in[9], 255,
            dtflag, WtC + s * 65536, 131072,
            bC + s * 256, bC + 2048 + s * 256, bC + 4096 + s * 256,
            bC + 6144 + s * 256, 512, 256, 256);
    }
    gemm_mfma<false, false, 256><<<dim3(256, 2, 8), blk, 0, stream>>>(
        z2, nullptr, B * 256, 1, 256, BIGK, 0, dtflag, WtC, 65536,
        bC, bC + 2048, bC + 4096, bC + 6144, 256,
        zb, B * 256, 256, stCs, stCq, 256, nullptr);

    // ---- Stage D prep+gemm, H prep (stC available) -----------------------
    prep_w<<<dim3(128, 4), blk, 0, stream>>>(
        d_in[18], 65536, d_in[19], 128, stCs, stCq, 512, d_in[6], d_in[7], 255,
        dtflag, WtD, 65536, bD, bD + 512, bD + 1024, bD + 1536, 128, 512, 512);
    prep_w<<<dim3(256, 4), blk, 0, stream>>>(
        d_in[26], 131072, d_in[27], 256, stCs, stCq, 512, d_in[6], d_in[7], 255,
        dtflag, WtH, 131072, bH, bH + 1024, bH + 2048, bH + 3072, 256, 512, 256);
    gemm_mfma<false, false, 512><<<dim3(256, 1, 4), blk, 0, stream>>>(
        zb, nullptr, 2 * B * 256, 3, 256, 256, B * 256, dtflag, WtD, 65536,
        bD, bD + 512, bD + 1024, bD + 1536, 128,
        za, B * 128, 128, stDs, stDq, 128, nullptr);

    // ---- Stage E/F: small gating layers (old VALU kernel) ----------------
    gemm_bn<true, 128, 64><<<dim3(512, 1, 4), blk, 0, stream>>>(
        za, B * 128, 128, PF(20), 128 * 64, PF(21), 64, zbb, B * 64,
        stEs, stEq, 64, stDs, stDq, 128, PF(10), PF(11), 127);
    gemm_bn<true, 64, 64><<<dim3(512, 1, 4), blk, 0, stream>>>(
        zbb, B * 64, 64, PF(22), 64 * 64, PF(23), 64, zc, B * 64,
        stFs, stFq, 64, stEs, stEq, 64, PF(12), PF(13), 63);

    // ---- Gate ------------------------------------------------------------
    gate_kernel<<<dim3(B_ROWS / 4, 4), blk, 0, stream>>>(
        zc, stFs, stFq, PF(12), PF(13), PF(24), PF(25), Y0);

    // ---- Stage H: combine, gate weights folded via dual accumulators -----
    gemm_mfma<false, true, 512><<<dim3(256, 2, 4), blk, 0, stream>>>(
        zb, nullptr, 2 * B * 256, 3, 256, 256, B * 256, dtflag, WtH, 131072,
        bH, bH + 1024, bH + 2048, bH + 3072, 256,
        zxc, B * 256, 256, stHs, stHq, 256, Y0);

    // ---- Output heads ----------------------------------------------------
    heads_kernel<<<dim3(B_ROWS / 4, 4), blk, 0, stream>>>(
        zxc, stHs, stHq, PF(6), PF(7), PF(28), PF(29), PF(30), PF(31),
        PF(32), PF(33), PF(34), PF(35), d_out, dtflag);
}